// Round 4
// baseline (297.551 us; speedup 1.0000x reference)
//
#include <hip/hip_runtime.h>

#define IN_FT 256
#define OUT_FT 64

// ---------------------------------------------------------------------------
// GEMM: fts[N,64] = seq[N,256] @ W[64,256]^T   (fp32 vector ALU; no fp32 MFMA)
// ---------------------------------------------------------------------------
constexpr int BN  = 64;   // nodes per block
constexpr int BK  = 32;   // k-chunk
constexpr int LDT = 68;   // padded LDS stride (floats)

__global__ __launch_bounds__(256) void gemm_kernel(
    const float* __restrict__ seq, const float* __restrict__ W,
    float* __restrict__ fts, int N)
{
    __shared__ float As[BK][LDT];   // [k][node]
    __shared__ float Bs[BK][LDT];   // [k][feat]
    const int t  = (int)threadIdx.x;
    const int tx = t & 15;
    const int ty = t >> 4;
    const int nodeBase = (int)blockIdx.x * BN;

    float acc[4][4];
#pragma unroll
    for (int i = 0; i < 4; ++i)
#pragma unroll
        for (int j = 0; j < 4; ++j) acc[i][j] = 0.f;

    for (int k0 = 0; k0 < IN_FT; k0 += BK) {
        for (int i = t; i < (BN * BK) / 4; i += 256) {
            int row = i >> 3;
            int c4  = i & 7;
            int gn  = nodeBase + row;
            float4 v = make_float4(0.f, 0.f, 0.f, 0.f);
            if (gn < N) v = *(const float4*)(seq + (size_t)gn * IN_FT + k0 + c4 * 4);
            As[c4 * 4 + 0][row] = v.x;
            As[c4 * 4 + 1][row] = v.y;
            As[c4 * 4 + 2][row] = v.z;
            As[c4 * 4 + 3][row] = v.w;
        }
        for (int i = t; i < (OUT_FT * BK) / 4; i += 256) {
            int row = i >> 3;
            int c4  = i & 7;
            float4 v = *(const float4*)(W + (size_t)row * IN_FT + k0 + c4 * 4);
            Bs[c4 * 4 + 0][row] = v.x;
            Bs[c4 * 4 + 1][row] = v.y;
            Bs[c4 * 4 + 2][row] = v.z;
            Bs[c4 * 4 + 3][row] = v.w;
        }
        __syncthreads();
#pragma unroll
        for (int k = 0; k < BK; ++k) {
            float4 av = *(const float4*)&As[k][ty * 4];
            float4 bv = *(const float4*)&Bs[k][tx * 4];
            float a4[4] = {av.x, av.y, av.z, av.w};
            float b4[4] = {bv.x, bv.y, bv.z, bv.w};
#pragma unroll
            for (int i = 0; i < 4; ++i)
#pragma unroll
                for (int j = 0; j < 4; ++j)
                    acc[i][j] = fmaf(a4[i], b4[j], acc[i][j]);
        }
        __syncthreads();
    }
#pragma unroll
    for (int i = 0; i < 4; ++i) {
        int gn = nodeBase + ty * 4 + i;
        if (gn < N) {
            float4 o = make_float4(acc[i][0], acc[i][1], acc[i][2], acc[i][3]);
            *(float4*)(fts + (size_t)gn * OUT_FT + tx * 4) = o;
        }
    }
}

// ---------------------------------------------------------------------------
// Edge scatter-add: one wave per 4 edges; lane = output feature.
// Per edge: wave-uniform (src,dst,val) loads -> coalesced 256B fts row read
// -> coalesced 256B global_atomic_add into out. 4-deep for MLP.
// ---------------------------------------------------------------------------
constexpr int EPW = 4;   // edges per wave

__global__ __launch_bounds__(256) void scatter_atomic_kernel(
    const float* __restrict__ fts, const int* __restrict__ src,
    const int* __restrict__ dst, const float* __restrict__ val,
    float* __restrict__ out, int E)
{
    const int w    = ((int)blockIdx.x * 256 + (int)threadIdx.x) >> 6;
    const int lane = (int)threadIdx.x & 63;
    const int base = w * EPW;
    if (base >= E) return;
    const int cnt = min(EPW, E - base);

    int   s[EPW];
    int   d[EPW];
    float v[EPW];
    float f[EPW];
#pragma unroll
    for (int j = 0; j < EPW; ++j) {
        if (j < cnt) {
            s[j] = src[base + j];
            d[j] = dst[base + j];
            v[j] = val[base + j];
        }
    }
#pragma unroll
    for (int j = 0; j < EPW; ++j) {
        if (j < cnt) f[j] = fts[(size_t)s[j] * OUT_FT + lane];
    }
#pragma unroll
    for (int j = 0; j < EPW; ++j) {
        if (j < cnt) atomicAdd(out + (size_t)d[j] * OUT_FT + lane, f[j] * v[j]);
    }
}

// ---------------------------------------------------------------------------
// Finalize: out = PReLU(out + bias), vectorized float4
// ---------------------------------------------------------------------------
__global__ __launch_bounds__(256) void finalize_kernel(
    float* __restrict__ out, const float* __restrict__ bias,
    const float* __restrict__ alpha, int n4)   // n4 = total elems / 4
{
    int i = (int)blockIdx.x * 256 + (int)threadIdx.x;
    if (i >= n4) return;
    float4 o = *(float4*)(out + (size_t)i * 4);
    const float4 b = *(const float4*)(bias + ((i & 15) * 4));
    const float a = alpha[0];
    o.x += b.x; o.y += b.y; o.z += b.z; o.w += b.w;
    o.x = (o.x >= 0.f) ? o.x : a * o.x;
    o.y = (o.y >= 0.f) ? o.y : a * o.y;
    o.z = (o.z >= 0.f) ? o.z : a * o.z;
    o.w = (o.w >= 0.f) ? o.w : a * o.w;
    *(float4*)(out + (size_t)i * 4) = o;
}

// ---------------------------------------------------------------------------
extern "C" void kernel_launch(void* const* d_in, const int* in_sizes, int n_in,
                              void* d_out, int out_size, void* d_ws, size_t ws_size,
                              hipStream_t stream) {
    const float* seq      = (const float*)d_in[0];
    const float* W        = (const float*)d_in[1];
    const float* bias     = (const float*)d_in[2];
    const float* alpha    = (const float*)d_in[3];
    const int*   edge_src = (const int*)d_in[4];
    const int*   edge_dst = (const int*)d_in[5];
    const float* edge_val = (const float*)d_in[6];
    float* out = (float*)d_out;

    const int N = in_sizes[0] / IN_FT;
    const int E = in_sizes[4];

    float* fts = (float*)d_ws;   // N * OUT_FT floats

    // zero the output accumulator (graph-capture-safe async memset)
    hipMemsetAsync(out, 0, (size_t)N * OUT_FT * sizeof(float), stream);

    const int gemm_blocks = (N + BN - 1) / BN;
    gemm_kernel<<<gemm_blocks, 256, 0, stream>>>(seq, W, fts, N);

    const int waves = (E + EPW - 1) / EPW;
    const int sblocks = (waves + 3) / 4;            // 4 waves per 256-thread block
    scatter_atomic_kernel<<<sblocks, 256, 0, stream>>>(
        fts, edge_src, edge_dst, edge_val, out, E);

    const int n4 = (N * OUT_FT) / 4;
    finalize_kernel<<<(n4 + 255) / 256, 256, 0, stream>>>(out, bias, alpha, n4);
}

// Round 5
// 244.214 us; speedup vs baseline: 1.2184x; 1.2184x over previous
//
#include <hip/hip_runtime.h>

#define IN_FT 256
#define OUT_FT 64

// ---------------------------------------------------------------------------
// GEMM: fts[N,64] = seq[N,256] @ W[64,256]^T   (fp32 vector ALU; no fp32 MFMA)
// ---------------------------------------------------------------------------
constexpr int BN  = 64;   // nodes per block
constexpr int BK  = 32;   // k-chunk
constexpr int LDT = 68;   // padded LDS stride (floats)

__global__ __launch_bounds__(256) void gemm_kernel(
    const float* __restrict__ seq, const float* __restrict__ W,
    float* __restrict__ fts, int N)
{
    __shared__ float As[BK][LDT];   // [k][node]
    __shared__ float Bs[BK][LDT];   // [k][feat]
    const int t  = (int)threadIdx.x;
    const int tx = t & 15;
    const int ty = t >> 4;
    const int nodeBase = (int)blockIdx.x * BN;

    float acc[4][4];
#pragma unroll
    for (int i = 0; i < 4; ++i)
#pragma unroll
        for (int j = 0; j < 4; ++j) acc[i][j] = 0.f;

    for (int k0 = 0; k0 < IN_FT; k0 += BK) {
        for (int i = t; i < (BN * BK) / 4; i += 256) {
            int row = i >> 3;
            int c4  = i & 7;
            int gn  = nodeBase + row;
            float4 v = make_float4(0.f, 0.f, 0.f, 0.f);
            if (gn < N) v = *(const float4*)(seq + (size_t)gn * IN_FT + k0 + c4 * 4);
            As[c4 * 4 + 0][row] = v.x;
            As[c4 * 4 + 1][row] = v.y;
            As[c4 * 4 + 2][row] = v.z;
            As[c4 * 4 + 3][row] = v.w;
        }
        for (int i = t; i < (OUT_FT * BK) / 4; i += 256) {
            int row = i >> 3;
            int c4  = i & 7;
            float4 v = *(const float4*)(W + (size_t)row * IN_FT + k0 + c4 * 4);
            Bs[c4 * 4 + 0][row] = v.x;
            Bs[c4 * 4 + 1][row] = v.y;
            Bs[c4 * 4 + 2][row] = v.z;
            Bs[c4 * 4 + 3][row] = v.w;
        }
        __syncthreads();
#pragma unroll
        for (int k = 0; k < BK; ++k) {
            float4 av = *(const float4*)&As[k][ty * 4];
            float4 bv = *(const float4*)&Bs[k][tx * 4];
            float a4[4] = {av.x, av.y, av.z, av.w};
            float b4[4] = {bv.x, bv.y, bv.z, bv.w};
#pragma unroll
            for (int i = 0; i < 4; ++i)
#pragma unroll
                for (int j = 0; j < 4; ++j)
                    acc[i][j] = fmaf(a4[i], b4[j], acc[i][j]);
        }
        __syncthreads();
    }
#pragma unroll
    for (int i = 0; i < 4; ++i) {
        int gn = nodeBase + ty * 4 + i;
        if (gn < N) {
            float4 o = make_float4(acc[i][0], acc[i][1], acc[i][2], acc[i][3]);
            *(float4*)(fts + (size_t)gn * OUT_FT + tx * 4) = o;
        }
    }
}

// ---------------------------------------------------------------------------
// CSR build: histogram -> hierarchical scan -> scatter (packed 8B pairs)
// ---------------------------------------------------------------------------
__global__ void zero2_i(int* __restrict__ a, int* __restrict__ b, int n) {
    int i = (int)blockIdx.x * 256 + (int)threadIdx.x;
    if (i < n) { a[i] = 0; b[i] = 0; }
}

__global__ void hist_kernel(const int* __restrict__ dst, int* __restrict__ counts, int E) {
    int e = (int)blockIdx.x * 256 + (int)threadIdx.x;
    if (e < E) atomicAdd(&counts[dst[e]], 1);
}

__device__ __forceinline__ int block_excl_scan_256(int v, int t) {
    int lane = t & 63, wv = t >> 6;
    int incl = v;
#pragma unroll
    for (int d = 1; d < 64; d <<= 1) {
        int u = __shfl_up(incl, d, 64);
        if (lane >= d) incl += u;
    }
    __shared__ int wsum[4];
    if (lane == 63) wsum[wv] = incl;
    __syncthreads();
    int woff = 0;
    for (int i = 0; i < wv; ++i) woff += wsum[i];
    return woff + incl - v;
}

__global__ __launch_bounds__(256) void block_sum_kernel(
    const int* __restrict__ counts, int* __restrict__ blockSum, int N)
{
    const int t = (int)threadIdx.x;
    const int base = (int)blockIdx.x * 1024 + t * 4;
    int s = 0;
    if (base + 3 < N) {
        int4 v = *(const int4*)(counts + base);
        s = v.x + v.y + v.z + v.w;
    } else {
        for (int j = 0; j < 4; ++j) if (base + j < N) s += counts[base + j];
    }
    int lane = t & 63, wv = t >> 6;
#pragma unroll
    for (int d = 32; d >= 1; d >>= 1) s += __shfl_down(s, d, 64);
    __shared__ int wsum[4];
    if (lane == 0) wsum[wv] = s;
    __syncthreads();
    if (t == 0) blockSum[blockIdx.x] = wsum[0] + wsum[1] + wsum[2] + wsum[3];
}

__global__ __launch_bounds__(256) void scan_blocks_kernel(
    const int* __restrict__ blockSum, int* __restrict__ blockOff,
    int* __restrict__ offsets, int NB, int N)
{
    const int t = (int)threadIdx.x;
    int v = (t < NB) ? blockSum[t] : 0;
    int excl = block_excl_scan_256(v, t);
    if (t < NB) blockOff[t] = excl;
    if (t == 255) offsets[N] = excl + v;
}

__global__ __launch_bounds__(256) void scan_write_kernel(
    const int* __restrict__ counts, const int* __restrict__ blockOff,
    int* __restrict__ offsets, int N)
{
    const int t = (int)threadIdx.x;
    const int base = (int)blockIdx.x * 1024 + t * 4;
    int4 v = make_int4(0, 0, 0, 0);
    if (base + 3 < N) {
        v = *(const int4*)(counts + base);
    } else {
        if (base + 0 < N) v.x = counts[base + 0];
        if (base + 1 < N) v.y = counts[base + 1];
        if (base + 2 < N) v.z = counts[base + 2];
    }
    int s = v.x + v.y + v.z + v.w;
    int p = block_excl_scan_256(s, t) + blockOff[blockIdx.x];
    if (base + 0 < N) offsets[base + 0] = p;
    if (base + 1 < N) offsets[base + 1] = p + v.x;
    if (base + 2 < N) offsets[base + 2] = p + v.x + v.y;
    if (base + 3 < N) offsets[base + 3] = p + v.x + v.y + v.z;
}

// packed (src, val) pair: single 8B store per edge -> one 64B line touch
__global__ void scatter_csr_kernel(
    const int* __restrict__ src, const int* __restrict__ dst,
    const float* __restrict__ val, const int* __restrict__ offsets,
    int* __restrict__ cursor, int2* __restrict__ csr_pair, int E)
{
    int e = (int)blockIdx.x * 256 + (int)threadIdx.x;
    if (e < E) {
        int d = dst[e];
        int pos = offsets[d] + atomicAdd(&cursor[d], 1);
        int2 pr;
        pr.x = src[e];
        pr.y = __float_as_int(val[e]);
        csr_pair[pos] = pr;
    }
}

// ---------------------------------------------------------------------------
// Gather-reduce: one wave per dst node, lane = output feature.
// Packed pairs staged cooperatively (one coalesced 8B load per <=64 edges),
// broadcast via shfl; fts gathers issued 4-deep for MLP.
// ---------------------------------------------------------------------------
__global__ __launch_bounds__(256) void gather_kernel(
    const float* __restrict__ fts, const int* __restrict__ offsets,
    const int2* __restrict__ csr_pair,
    const float* __restrict__ bias, const float* __restrict__ alpha,
    float* __restrict__ out, int N)
{
    int gtid = (int)blockIdx.x * 256 + (int)threadIdx.x;
    int node = gtid >> 6;
    int lane = gtid & 63;
    if (node >= N) return;
    int e0 = offsets[node];
    int deg = offsets[node + 1] - e0;
    float acc = 0.f;

    for (int base = 0; base < deg; base += 64) {
        int rem = deg - base;
        int cnt = rem < 64 ? rem : 64;
        int   sReg = 0;
        float vReg = 0.f;
        if (lane < cnt) {
            int2 pr = csr_pair[e0 + base + lane];
            sReg = pr.x;
            vReg = __int_as_float(pr.y);
        }
        int j = 0;
        for (; j + 4 <= cnt; j += 4) {
            int   s0 = __shfl(sReg, j + 0, 64);
            int   s1 = __shfl(sReg, j + 1, 64);
            int   s2 = __shfl(sReg, j + 2, 64);
            int   s3 = __shfl(sReg, j + 3, 64);
            float v0 = __shfl(vReg, j + 0, 64);
            float v1 = __shfl(vReg, j + 1, 64);
            float v2 = __shfl(vReg, j + 2, 64);
            float v3 = __shfl(vReg, j + 3, 64);
            float f0 = fts[(size_t)s0 * OUT_FT + lane];
            float f1 = fts[(size_t)s1 * OUT_FT + lane];
            float f2 = fts[(size_t)s2 * OUT_FT + lane];
            float f3 = fts[(size_t)s3 * OUT_FT + lane];
            acc = fmaf(f0, v0, acc);
            acc = fmaf(f1, v1, acc);
            acc = fmaf(f2, v2, acc);
            acc = fmaf(f3, v3, acc);
        }
        for (; j < cnt; ++j) {
            int   sj = __shfl(sReg, j, 64);
            float vj = __shfl(vReg, j, 64);
            acc = fmaf(fts[(size_t)sj * OUT_FT + lane], vj, acc);
        }
    }
    float o = acc + bias[lane];
    float a = alpha[0];
    out[(size_t)node * OUT_FT + lane] = (o >= 0.f) ? o : a * o;
}

// ---------------------------------------------------------------------------
extern "C" void kernel_launch(void* const* d_in, const int* in_sizes, int n_in,
                              void* d_out, int out_size, void* d_ws, size_t ws_size,
                              hipStream_t stream) {
    const float* seq      = (const float*)d_in[0];
    const float* W        = (const float*)d_in[1];
    const float* bias     = (const float*)d_in[2];
    const float* alpha    = (const float*)d_in[3];
    const int*   edge_src = (const int*)d_in[4];
    const int*   edge_dst = (const int*)d_in[5];
    const float* edge_val = (const float*)d_in[6];
    float* out = (float*)d_out;

    const int N = in_sizes[0] / IN_FT;
    const int E = in_sizes[4];
    const int NB = (N + 1023) / 1024;

    size_t off = 0;
    auto take = [&](size_t bytes) -> char* {
        char* p = (char*)d_ws + off;
        off += (bytes + 255) & ~(size_t)255;
        return p;
    };
    float* fts      = (float*)take((size_t)N * OUT_FT * sizeof(float));
    int*   counts   = (int*)take((size_t)N * sizeof(int));
    int*   offsets  = (int*)take(((size_t)N + 1) * sizeof(int));
    int*   cursor   = (int*)take((size_t)N * sizeof(int));
    int*   blockSum = (int*)take((size_t)NB * sizeof(int));
    int*   blockOff = (int*)take((size_t)NB * sizeof(int));
    int2*  csr_pair = (int2*)take((size_t)E * sizeof(int2));
    (void)ws_size;

    const int gemm_blocks = (N + BN - 1) / BN;
    gemm_kernel<<<gemm_blocks, 256, 0, stream>>>(seq, W, fts, N);

    zero2_i<<<(N + 255) / 256, 256, 0, stream>>>(counts, cursor, N);
    hist_kernel<<<(E + 255) / 256, 256, 0, stream>>>(edge_dst, counts, E);
    block_sum_kernel<<<NB, 256, 0, stream>>>(counts, blockSum, N);
    scan_blocks_kernel<<<1, 256, 0, stream>>>(blockSum, blockOff, offsets, NB, N);
    scan_write_kernel<<<NB, 256, 0, stream>>>(counts, blockOff, offsets, N);
    scatter_csr_kernel<<<(E + 255) / 256, 256, 0, stream>>>(
        edge_src, edge_dst, edge_val, offsets, cursor, csr_pair, E);
    gather_kernel<<<((size_t)N * 64 + 255) / 256, 256, 0, stream>>>(
        fts, offsets, csr_pair, bias, alpha, out, N);
}